// Round 12
// baseline (3483.791 us; speedup 1.0000x reference)
//
#include <hip/hip_runtime.h>

#define T_   500
#define B_   32
#define IN_  512
#define H_   1024
#define NWG  128    // total WGs (64 per direction)
#define NPD  64     // WGs per direction
#define THR  512    // threads per WG (8 waves)

typedef _Float16 f16x8 __attribute__((ext_vector_type(8)));
typedef float    f32x4 __attribute__((ext_vector_type(4)));

#define MFMA __builtin_amdgcn_mfma_f32_16x16x32_f16

// counted vmem wait + scheduling fence (rule #18: uses must not slip past the wait)
#define WAITV(N) do { asm volatile("s_waitcnt vmcnt(" #N ")" ::: "memory"); \
                      __builtin_amdgcn_sched_barrier(0); } while (0)

// cached x-fragment load (asm so vmcnt bookkeeping is exact)
#define XLOAD(r) asm volatile("global_load_dwordx4 %0, %1, off offset:%2" \
  : "=v"(xa##r) : "v"(aXn), "i"(64*(r)) : "memory")

// coherent (MALL-bypass) h-fragment load
#define HLOAD(r) asm volatile("global_load_dwordx4 %0, %1, off offset:%2 sc0 sc1" \
  : "=v"(hf##r) : "v"(aH), "i"(64*(r)) : "memory")

// coherent flag load (poll)
#define FLOAD(v) asm volatile("global_load_dword %0, %1, off sc0 sc1" \
  : "=v"(v) : "v"(fp) : "memory")

// one x k-step: A-frag xa##r against 4 gate-tile register B-frags
#define XSTEP(r) do { \
  acc0 = MFMA(xa##r, xw0[r], acc0, 0, 0, 0); \
  acc1 = MFMA(xa##r, xw1[r], acc1, 0, 0, 0); \
  acc2 = MFMA(xa##r, xw2[r], acc2, 0, 0, 0); \
  acc3 = MFMA(xa##r, xw3[r], acc3, 0, 0, 0); } while (0)

// one h k-step: A-frag against 4 n-tile B-frags from swizzled LDS
#define HSTEP(r, ks) do { \
  const int t_ = (kq512 + (ks) * 64 + fkb16) ^ sw; \
  acc0 = MFMA(hf##r, *(const f16x8*)(WhB0 + t_), acc0, 0, 0, 0); \
  acc1 = MFMA(hf##r, *(const f16x8*)(WhB1 + t_), acc1, 0, 0, 0); \
  acc2 = MFMA(hf##r, *(const f16x8*)(WhB2 + t_), acc2, 0, 0, 0); \
  acc3 = MFMA(hf##r, *(const f16x8*)(WhB3 + t_), acc3, 0, 0, 0); } while (0)

__device__ __forceinline__ f16x8 cvt8(float4 lo, float4 hi) {
  return (f16x8){ (_Float16)lo.x, (_Float16)lo.y, (_Float16)lo.z, (_Float16)lo.w,
                  (_Float16)hi.x, (_Float16)hi.y, (_Float16)hi.z, (_Float16)hi.w };
}

// ---------------------------------------------------------------- x -> fp16
__global__ void cvt_x_kernel(const float* __restrict__ x, _Float16* __restrict__ xb, int n8) {
  int i = blockIdx.x * blockDim.x + threadIdx.x;
  if (i >= n8) return;
  const float4* p = (const float4*)x + (size_t)i * 2;
  *((f16x8*)xb + i) = cvt8(p[0], p[1]);
}

// ---------------------------------------------------------------- persistent LSTM
__global__ __launch_bounds__(THR, 1) void lstm_kernel(
    const float* __restrict__ w_ih_f, const float* __restrict__ w_hh_f,
    const float* __restrict__ b_ih_f, const float* __restrict__ b_hh_f,
    const float* __restrict__ w_ih_r, const float* __restrict__ w_hh_r,
    const float* __restrict__ b_ih_r, const float* __restrict__ b_hh_r,
    const _Float16* __restrict__ xb, _Float16* __restrict__ hb,
    unsigned* __restrict__ flags, float* __restrict__ out)
{
  __shared__ _Float16 Wh[64 * 1024];   // 131,072 B : h-weights, XOR-swizzled rows
  __shared__ float    pg[4][32][64];   //  32,768 B : K-quarter partial gates
  // total 163,840 B = 160 KiB (device max)

  const int wg   = blockIdx.x;
  const int dir  = wg >> 6;
  const int slot = wg & 63;
  const int col0 = slot * 16;          // first owned h-column (16 per WG)
  const int tid  = threadIdx.x;

  const float* w_ih = dir ? w_ih_r : w_ih_f;
  const float* w_hh = dir ? w_hh_r : w_hh_f;
  const float* b_ih = dir ? b_ih_r : b_ih_f;
  const float* b_hh = dir ? b_hh_r : b_hh_f;

  unsigned* fl = flags + dir * NPD;    // this direction's 64 arrival flags

  // ---- stage h-weights into LDS, fp16, row r -> gate row (r>>4)*H + col0 + (r&15),
  //      byte offset r*2048 + ((k*2) ^ ((r&7)<<4))  (swizzled, 16B-aligned)
  for (int i = tid; i < 64 * 128; i += THR) {
    const int r  = i >> 7;
    const int k  = (i & 127) * 8;
    const int gr = (r >> 4) * H_ + col0 + (r & 15);
    const float4* p = (const float4*)(w_hh + (size_t)gr * H_ + k);
    const int byte = r * 2048 + ((k * 2) ^ ((r & 7) << 4));
    *(f16x8*)((char*)Wh + byte) = cvt8(p[0], p[1]);
  }

  // ---- wave tiling: wave = (m-half, K-quarter); each wave does all 4 n-tiles ----
  const int lane = tid & 63, wv = tid >> 6;
  const int mh = wv & 1, kq = wv >> 1;       // m-half (batch), K-quarter
  const int frow = lane & 15, fkb = lane >> 4;
  const int mrow = mh * 16 + frow;           // batch row this lane supplies
  const int sw    = (frow & 7) << 4;         // LDS row swizzle
  const int kq512 = kq * 512;                // h k-quarter byte base in LDS row
  const int fkb16 = fkb * 16;
  const char* WhB0 = (const char*)Wh + (size_t)( 0 + frow) * 2048;
  const char* WhB1 = (const char*)Wh + (size_t)(16 + frow) * 2048;
  const char* WhB2 = (const char*)Wh + (size_t)(32 + frow) * 2048;
  const char* WhB3 = (const char*)Wh + (size_t)(48 + frow) * 2048;

  // ---- x-weights: resident in registers (16 B-frags = 64 VGPRs), fp32 -> fp16 once
  f16x8 xw0[4], xw1[4], xw2[4], xw3[4];
#pragma unroll
  for (int ks = 0; ks < 4; ++ks) {
    const int k = kq * 128 + ks * 32 + fkb * 8;
    { const float4* p = (const float4*)(w_ih + (size_t)(0 * H_ + col0 + frow) * IN_ + k);
      xw0[ks] = cvt8(p[0], p[1]); }
    { const float4* p = (const float4*)(w_ih + (size_t)(1 * H_ + col0 + frow) * IN_ + k);
      xw1[ks] = cvt8(p[0], p[1]); }
    { const float4* p = (const float4*)(w_ih + (size_t)(2 * H_ + col0 + frow) * IN_ + k);
      xw2[ks] = cvt8(p[0], p[1]); }
    { const float4* p = (const float4*)(w_ih + (size_t)(3 * H_ + col0 + frow) * IN_ + k);
      xw3[ks] = cvt8(p[0], p[1]); }
  }

  // ---- per-thread (b, h-col) ownership for gates/state ----
  const int tb = tid >> 4, thc = tid & 15, tcol = col0 + thc;
  const float b0 = b_ih[0 * H_ + tcol] + b_hh[0 * H_ + tcol];
  const float b1 = b_ih[1 * H_ + tcol] + b_hh[1 * H_ + tcol];
  const float b2 = b_ih[2 * H_ + tcol] + b_hh[2 * H_ + tcol];
  const float b3 = b_ih[3 * H_ + tcol] + b_hh[3 * H_ + tcol];
  float c = 0.f;

  const size_t hbase = (size_t)(dir * 2) * B_ * H_;

  __syncthreads();   // weights staged

  // prologue: issue x-loads for s = 0
  const _Float16* aXn = xb + ((size_t)(dir ? (T_ - 1) : 0) * B_ + mrow) * IN_ + kq * 128 + fkb * 8;
  f16x8 xa0, xa1, xa2, xa3;
  XLOAD(0); XLOAD(1); XLOAD(2); XLOAD(3);

  for (int s = 0; s < T_; ++s) {
    const int tx = dir ? (T_ - 1 - s) : s;

    // ===== A: consume x-loads, keep last step's publish stores in flight =====
    if (s) { WAITV(2); } else { WAITV(0); }
    f32x4 acc0 = {0,0,0,0}, acc1 = {0,0,0,0}, acc2 = {0,0,0,0}, acc3 = {0,0,0,0};
    XSTEP(0); XSTEP(1); XSTEP(2); XSTEP(3);

    f16x8 hf0, hf1, hf2, hf3, hf4, hf5, hf6, hf7;
    if (s > 0) {
      // ===== B: residual ack of h(s) publishes (aged under x-part), then flag =====
      WAITV(0);
      __builtin_amdgcn_s_barrier();   // all 8 waves ack'd -> h(s) MALL-visible
      if (tid == 0)
        __hip_atomic_store(fl + slot, (unsigned)s, __ATOMIC_RELAXED, __HIP_MEMORY_SCOPE_AGENT);

      // ===== C: depth-2 flag poll (wv0 only; 64 flags on 4 lines, proven cheap) =====
      if (wv == 0) {
        const unsigned* fp = fl + lane;
        const unsigned tgt = (unsigned)s;
        unsigned fa, fb;
        int guard = 0;
        FLOAD(fa);
        for (;;) {
          FLOAD(fb);
          WAITV(1);                                   // fa ready (half-RTT offset)
          if (__all(fa >= tgt)) { WAITV(0); break; }
          FLOAD(fa);
          WAITV(1);                                   // fb ready
          if (__all(fb >= tgt)) { WAITV(0); break; }
          if ((guard += 2) > (1 << 22)) { WAITV(0); break; }  // failsafe
        }
      }
      __builtin_amdgcn_s_barrier();
      asm volatile("" ::: "memory");   // no load hoisting above the gate

      // ===== D: single gated bulk load, counted pipeline (R5-exact) =====
      const _Float16* aH = hb + hbase + (size_t)((s & 1) * B_ + mrow) * H_ + kq * 256 + fkb * 8;
      HLOAD(0); HLOAD(1); HLOAD(2); HLOAD(3);
      HLOAD(4); HLOAD(5); HLOAD(6); HLOAD(7);
      WAITV(4);
      HSTEP(0, 0); HSTEP(1, 1); HSTEP(2, 2); HSTEP(3, 3);
      WAITV(0);
      HSTEP(4, 4); HSTEP(5, 5); HSTEP(6, 6); HSTEP(7, 7);
    }

    // ===== E: partial-gate exchange + gates =====
#pragma unroll
    for (int i = 0; i < 4; ++i) {
      const int m = mh * 16 + fkb * 4 + i;
      pg[kq][m][ 0 + frow] = acc0[i];
      pg[kq][m][16 + frow] = acc1[i];
      pg[kq][m][32 + frow] = acc2[i];
      pg[kq][m][48 + frow] = acc3[i];
    }
    asm volatile("s_waitcnt lgkmcnt(0)" ::: "memory");
    __builtin_amdgcn_s_barrier();
    __builtin_amdgcn_sched_barrier(0);

    float xi = pg[0][tb][ 0 + thc] + pg[1][tb][ 0 + thc] + pg[2][tb][ 0 + thc] + pg[3][tb][ 0 + thc] + b0;
    float xf = pg[0][tb][16 + thc] + pg[1][tb][16 + thc] + pg[2][tb][16 + thc] + pg[3][tb][16 + thc] + b1;
    float xg = pg[0][tb][32 + thc] + pg[1][tb][32 + thc] + pg[2][tb][32 + thc] + pg[3][tb][32 + thc] + b2;
    float xo = pg[0][tb][48 + thc] + pg[1][tb][48 + thc] + pg[2][tb][48 + thc] + pg[3][tb][48 + thc] + b3;
    float ig = fminf(fmaxf(0.2f * xi + 0.5f, 0.f), 1.f);
    float fg = fminf(fmaxf(0.2f * xf + 0.5f, 0.f), 1.f);
    float cg = fminf(fmaxf(xg, -1.f), 1.f);
    float og = fminf(fmaxf(0.2f * xo + 0.5f, 0.f), 1.f);
    c = fg * c + ig * cg;
    float hv = og * fminf(fmaxf(c, -1.f), 1.f);

    // ===== F: prefetch next x-fragments FIRST (loads ahead of stores in the
    //          vmcnt queue so A's WAITV(2) consumes loads without draining stores)
    const int sn  = (s + 1 < T_) ? (s + 1) : s;        // clamp (last prefetch unused)
    const int txn = dir ? (T_ - 1 - sn) : sn;
    aXn = xb + ((size_t)txn * B_ + mrow) * IN_ + kq * 128 + fkb * 8;
    XLOAD(0); XLOAD(1); XLOAD(2); XLOAD(3);

    { // h publish: write-through to MALL; ack deferred to next step's B (hidden)
      const _Float16* hp = hb + hbase + (size_t)(((s + 1) & 1) * B_ + tb) * H_ + tcol;
      unsigned hbits = (unsigned)__builtin_bit_cast(unsigned short, (_Float16)hv);
      asm volatile("global_store_short %0, %1, off sc0 sc1" :: "v"(hp), "v"(hbits) : "memory");
    }
    out[((size_t)tx * B_ + tb) * (2 * H_) + dir * H_ + tcol] = hv;   // plain cached store
    if (s == T_ - 1) {
      const size_t HY = (size_t)T_ * B_ * 2 * H_;
      out[HY + ((size_t)dir * B_ + tb) * H_ + tcol] = hv;                           // hy
      out[HY + (size_t)2 * B_ * H_ + ((size_t)dir * B_ + tb) * H_ + tcol] = c;      // cy
    }
    // no tail barrier: next step's B/C barriers order pg WAR
  }
}

// ---------------------------------------------------------------- launcher
extern "C" void kernel_launch(void* const* d_in, const int* in_sizes, int n_in,
                              void* d_out, int out_size, void* d_ws, size_t ws_size,
                              hipStream_t stream) {
  const float* x      = (const float*)d_in[0];
  const float* w_ih_f = (const float*)d_in[1];
  const float* w_hh_f = (const float*)d_in[2];
  const float* b_ih_f = (const float*)d_in[3];
  const float* b_hh_f = (const float*)d_in[4];
  const float* w_ih_r = (const float*)d_in[5];
  const float* w_hh_r = (const float*)d_in[6];
  const float* b_ih_r = (const float*)d_in[7];
  const float* b_hh_r = (const float*)d_in[8];
  float* out = (float*)d_out;

  char* ws = (char*)d_ws;
  _Float16* xb    = (_Float16*)ws;                        // 16,384,000 B  (T*B*IN f16)
  _Float16* hb    = (_Float16*)(ws + 16384000);           //    262,144 B  (2 dir * 2 buf * B * H f16)
  unsigned* flags = (unsigned*)(ws + 16384000 + 262144);  //      1,024 B  (2 dir * 64 flags)

  hipMemsetAsync(flags, 0, 1024, stream);                 // clear flags every launch/replay
  cvt_x_kernel<<<4000, 256, 0, stream>>>(x, xb, 1024000);
  lstm_kernel<<<NWG, THR, 0, stream>>>(w_ih_f, w_hh_f, b_ih_f, b_hh_f,
                                       w_ih_r, w_hh_r, b_ih_r, b_hh_r,
                                       xb, hb, flags, out);
}

// Round 13
// 2316.776 us; speedup vs baseline: 1.5037x; 1.5037x over previous
//
#include <hip/hip_runtime.h>

#define T_   500
#define B_   32
#define IN_  512
#define H_   1024
#define NWG  128    // total WGs (64 per direction)
#define NPD  64     // WGs per direction
#define THR  512    // threads per WG (8 waves)

typedef _Float16 f16x8 __attribute__((ext_vector_type(8)));
typedef float    f32x4 __attribute__((ext_vector_type(4)));

#define MFMA __builtin_amdgcn_mfma_f32_16x16x32_f16

// counted vmem wait + scheduling fence (rule #18: MFMA hoists past bare asm waitcnt)
#define WAITV(N) do { asm volatile("s_waitcnt vmcnt(" #N ")" ::: "memory"); \
                      __builtin_amdgcn_sched_barrier(0); } while (0)

// coherent (MALL) 16B load of h fragment: bypasses L1/L2 -> no acquire-invalidate needed
#define HLOAD(r, ks) \
  asm volatile("global_load_dwordx4 %0, %1, off offset:%2 sc0 sc1" \
               : "=v"(hf##r) : "v"(aH), "i"(64 * (ks)) : "memory")

// one h k-step: A-frag hf##r against 4 n-tile B-frags from swizzled LDS
#define HSTEP(r, ks) do { \
  const int t_ = (kq512 + (ks) * 64 + fkb16) ^ sw; \
  acc0 = MFMA(hf##r, *(const f16x8*)(WhB0 + t_), acc0, 0, 0, 0); \
  acc1 = MFMA(hf##r, *(const f16x8*)(WhB1 + t_), acc1, 0, 0, 0); \
  acc2 = MFMA(hf##r, *(const f16x8*)(WhB2 + t_), acc2, 0, 0, 0); \
  acc3 = MFMA(hf##r, *(const f16x8*)(WhB3 + t_), acc3, 0, 0, 0); } while (0)

__device__ __forceinline__ f16x8 cvt8(float4 lo, float4 hi) {
  return (f16x8){ (_Float16)lo.x, (_Float16)lo.y, (_Float16)lo.z, (_Float16)lo.w,
                  (_Float16)hi.x, (_Float16)hi.y, (_Float16)hi.z, (_Float16)hi.w };
}

// ---------------------------------------------------------------- x -> fp16
__global__ void cvt_x_kernel(const float* __restrict__ x, _Float16* __restrict__ xb, int n8) {
  int i = blockIdx.x * blockDim.x + threadIdx.x;
  if (i >= n8) return;
  const float4* p = (const float4*)x + (size_t)i * 2;
  *((f16x8*)xb + i) = cvt8(p[0], p[1]);
}

// ---------------------------------------------------------------- persistent LSTM
__global__ __launch_bounds__(THR, 1) void lstm_kernel(
    const float* __restrict__ w_ih_f, const float* __restrict__ w_hh_f,
    const float* __restrict__ b_ih_f, const float* __restrict__ b_hh_f,
    const float* __restrict__ w_ih_r, const float* __restrict__ w_hh_r,
    const float* __restrict__ b_ih_r, const float* __restrict__ b_hh_r,
    const _Float16* __restrict__ xb, _Float16* __restrict__ hb,
    unsigned* __restrict__ flags, float* __restrict__ out)
{
  __shared__ _Float16 Wh[64 * 1024];   // 131,072 B : h-weights, XOR-swizzled rows
  __shared__ float    pgT[4][64][32];  //  32,768 B : partial gates, [kq][col][m^swz]
  // total 163,840 B = 160 KiB (device max)

  const int wg   = blockIdx.x;
  const int dir  = wg >> 6;
  const int slot = wg & 63;
  const int col0 = slot * 16;          // first owned h-column (16 per WG)
  const int tid  = threadIdx.x;

  const float* w_ih = dir ? w_ih_r : w_ih_f;
  const float* w_hh = dir ? w_hh_r : w_hh_f;
  const float* b_ih = dir ? b_ih_r : b_ih_f;
  const float* b_hh = dir ? b_hh_r : b_hh_f;

  unsigned* fl = flags + dir * NPD;    // this direction's 64 arrival flags

  // ---- stage h-weights into LDS, fp16, row r -> gate row (r>>4)*H + col0 + (r&15),
  //      byte offset r*2048 + ((k*2) ^ ((r&7)<<4))  (swizzled, 16B-aligned)
  for (int i = tid; i < 64 * 128; i += THR) {
    const int r  = i >> 7;
    const int k  = (i & 127) * 8;
    const int gr = (r >> 4) * H_ + col0 + (r & 15);
    const float4* p = (const float4*)(w_hh + (size_t)gr * H_ + k);
    const int byte = r * 2048 + ((k * 2) ^ ((r & 7) << 4));
    *(f16x8*)((char*)Wh + byte) = cvt8(p[0], p[1]);
  }

  // ---- wave tiling: wave = (m-half, K-quarter); each wave does all 4 n-tiles ----
  const int lane = tid & 63, wv = tid >> 6;
  const int mh = wv & 1, kq = wv >> 1;       // m-half (batch), K-quarter
  const int frow = lane & 15, fkb = lane >> 4;
  const int mrow = mh * 16 + frow;           // batch row this lane supplies
  const int sw    = (frow & 7) << 4;         // LDS row swizzle (Wh)
  const int kq512 = kq * 512;                // h k-quarter byte base in LDS row
  const int fkb16 = fkb * 16;
  const char* WhB0 = (const char*)Wh + (size_t)( 0 + frow) * 2048;
  const char* WhB1 = (const char*)Wh + (size_t)(16 + frow) * 2048;
  const char* WhB2 = (const char*)Wh + (size_t)(32 + frow) * 2048;
  const char* WhB3 = (const char*)Wh + (size_t)(48 + frow) * 2048;

  // pg write swizzle: m-block base (4-aligned) XOR'd by col&7
  const int m0s = (mh * 16 + fkb * 4) ^ ((frow & 7) << 2);

  // ---- x-weights: resident in registers (16 B-frags = 64 VGPRs), fp32 -> fp16 once
  f16x8 xw0[4], xw1[4], xw2[4], xw3[4];
#pragma unroll
  for (int ks = 0; ks < 4; ++ks) {
    const int k = kq * 128 + ks * 32 + fkb * 8;
    { const float4* p = (const float4*)(w_ih + (size_t)(0 * H_ + col0 + frow) * IN_ + k);
      xw0[ks] = cvt8(p[0], p[1]); }
    { const float4* p = (const float4*)(w_ih + (size_t)(1 * H_ + col0 + frow) * IN_ + k);
      xw1[ks] = cvt8(p[0], p[1]); }
    { const float4* p = (const float4*)(w_ih + (size_t)(2 * H_ + col0 + frow) * IN_ + k);
      xw2[ks] = cvt8(p[0], p[1]); }
    { const float4* p = (const float4*)(w_ih + (size_t)(3 * H_ + col0 + frow) * IN_ + k);
      xw3[ks] = cvt8(p[0], p[1]); }
  }

  // ---- per-thread (b, h-col) ownership for gates/state ----
  const int tb = tid >> 4, thc = tid & 15, tcol = col0 + thc;
  const int rsw = tb ^ ((thc & 7) << 2);     // pg read swizzle (same for all 4 gates)
  const float b0 = b_ih[0 * H_ + tcol] + b_hh[0 * H_ + tcol];
  const float b1 = b_ih[1 * H_ + tcol] + b_hh[1 * H_ + tcol];
  const float b2 = b_ih[2 * H_ + tcol] + b_hh[2 * H_ + tcol];
  const float b3 = b_ih[3 * H_ + tcol] + b_hh[3 * H_ + tcol];
  float c = 0.f;

  const size_t hbase = (size_t)(dir * 2) * B_ * H_;

  __syncthreads();   // weights staged

  for (int s = 0; s < T_; ++s) {
    const int tx = dir ? (T_ - 1 - s) : s;

    // ===== phase 1: x-part — cached A loads, register B =====
    const _Float16* aX = xb + ((size_t)tx * B_ + mrow) * IN_ + kq * 128 + fkb * 8;
    f32x4 acc0 = {0,0,0,0}, acc1 = {0,0,0,0}, acc2 = {0,0,0,0}, acc3 = {0,0,0,0};
#pragma unroll
    for (int ks = 0; ks < 4; ++ks) {
      f16x8 xa = *(const f16x8*)(aX + ks * 32);
      acc0 = MFMA(xa, xw0[ks], acc0, 0, 0, 0);
      acc1 = MFMA(xa, xw1[ks], acc1, 0, 0, 0);
      acc2 = MFMA(xa, xw2[ks], acc2, 0, 0, 0);
      acc3 = MFMA(xa, xw3[ks], acc3, 0, 0, 0);
    }
    __builtin_amdgcn_sched_barrier(0);   // keep x-part ahead of the wait

    if (s > 0) {
      // ===== phase 2: wait for h(s) published by all 64 WGs of this direction =====
      if (wv == 0) {
        const unsigned tgt = (unsigned)s;
        int guard = 0;
        for (;;) {
          unsigned f = __hip_atomic_load(fl + lane, __ATOMIC_RELAXED, __HIP_MEMORY_SCOPE_AGENT);
          if (__all(f >= tgt)) break;
          __builtin_amdgcn_s_sleep(1);
          if (++guard > (1 << 22)) break;   // failsafe: fail loud, not hang
        }
      }
      __syncthreads();
      asm volatile("" ::: "memory");

      // ===== phase 3: h-part — coherent bypass loads, depth-pipelined =====
      const _Float16* aH = hb + hbase + (size_t)((s & 1) * B_ + mrow) * H_ + kq * 256 + fkb * 8;
      f16x8 hf0, hf1, hf2, hf3, hf4, hf5, hf6, hf7;
      HLOAD(0, 0); HLOAD(1, 1); HLOAD(2, 2); HLOAD(3, 3);
      HLOAD(4, 4); HLOAD(5, 5); HLOAD(6, 6); HLOAD(7, 7);
      WAITV(4);
      HSTEP(0, 0); HSTEP(1, 1); HSTEP(2, 2); HSTEP(3, 3);
      WAITV(0);
      HSTEP(4, 4); HSTEP(5, 5); HSTEP(6, 6); HSTEP(7, 7);
    }

    // ===== partial-gate write: swizzled pgT, 4 x ds_write_b128, conflict-free =====
    *(f32x4*)&pgT[kq][ 0 + frow][m0s] = acc0;
    *(f32x4*)&pgT[kq][16 + frow][m0s] = acc1;
    *(f32x4*)&pgT[kq][32 + frow][m0s] = acc2;
    *(f32x4*)&pgT[kq][48 + frow][m0s] = acc3;
    __syncthreads();

    // ===== phase 4: gates / state update (thread = (batch tb, col thc)) =====
    float xi = pgT[0][ 0 + thc][rsw] + pgT[1][ 0 + thc][rsw] + pgT[2][ 0 + thc][rsw] + pgT[3][ 0 + thc][rsw] + b0;
    float xf = pgT[0][16 + thc][rsw] + pgT[1][16 + thc][rsw] + pgT[2][16 + thc][rsw] + pgT[3][16 + thc][rsw] + b1;
    float xg = pgT[0][32 + thc][rsw] + pgT[1][32 + thc][rsw] + pgT[2][32 + thc][rsw] + pgT[3][32 + thc][rsw] + b2;
    float xo = pgT[0][48 + thc][rsw] + pgT[1][48 + thc][rsw] + pgT[2][48 + thc][rsw] + pgT[3][48 + thc][rsw] + b3;
    float ig = fminf(fmaxf(0.2f * xi + 0.5f, 0.f), 1.f);
    float fg = fminf(fmaxf(0.2f * xf + 0.5f, 0.f), 1.f);
    float cg = fminf(fmaxf(xg, -1.f), 1.f);
    float og = fminf(fmaxf(0.2f * xo + 0.5f, 0.f), 1.f);
    c = fg * c + ig * cg;
    float hv = og * fminf(fmaxf(c, -1.f), 1.f);

    out[((size_t)tx * B_ + tb) * (2 * H_) + dir * H_ + tcol] = hv;   // plain cached store
    { // coherent h publish: write-through to MALL, buffer (s+1)&1
      const _Float16* hp = hb + hbase + (size_t)(((s + 1) & 1) * B_ + tb) * H_ + tcol;
      unsigned hbits = (unsigned)__builtin_bit_cast(unsigned short, (_Float16)hv);
      asm volatile("global_store_short %0, %1, off sc0 sc1" :: "v"(hp), "v"(hbits) : "memory");
    }
    if (s == T_ - 1) {
      const size_t HY = (size_t)T_ * B_ * 2 * H_;
      out[HY + ((size_t)dir * B_ + tb) * H_ + tcol] = hv;                           // hy
      out[HY + (size_t)2 * B_ * H_ + ((size_t)dir * B_ + tb) * H_ + tcol] = c;      // cy
    }

    // ===== phase 5: release + arrive (truthful flag: stores ack'd first) =====
    asm volatile("s_waitcnt vmcnt(0)" ::: "memory");   // own h store ack'd at MALL
    __syncthreads();                                   // all 512 threads ack'd; pg reads done
    if (tid == 0)
      __hip_atomic_store(fl + slot, (unsigned)(s + 1), __ATOMIC_RELAXED, __HIP_MEMORY_SCOPE_AGENT);
    // next iteration's x-part overlaps flag propagation
  }
}

// ---------------------------------------------------------------- launcher
extern "C" void kernel_launch(void* const* d_in, const int* in_sizes, int n_in,
                              void* d_out, int out_size, void* d_ws, size_t ws_size,
                              hipStream_t stream) {
  const float* x      = (const float*)d_in[0];
  const float* w_ih_f = (const float*)d_in[1];
  const float* w_hh_f = (const float*)d_in[2];
  const float* b_ih_f = (const float*)d_in[3];
  const float* b_hh_f = (const float*)d_in[4];
  const float* w_ih_r = (const float*)d_in[5];
  const float* w_hh_r = (const float*)d_in[6];
  const float* b_ih_r = (const float*)d_in[7];
  const float* b_hh_r = (const float*)d_in[8];
  float* out = (float*)d_out;

  char* ws = (char*)d_ws;
  _Float16* xb    = (_Float16*)ws;                        // 16,384,000 B  (T*B*IN f16)
  _Float16* hb    = (_Float16*)(ws + 16384000);           //    262,144 B  (2 dir * 2 buf * B * H f16)
  unsigned* flags = (unsigned*)(ws + 16384000 + 262144);  //      1,024 B  (2 dir * 64 flags)

  hipMemsetAsync(flags, 0, 1024, stream);
  cvt_x_kernel<<<4000, 256, 0, stream>>>(x, xb, 1024000);
  lstm_kernel<<<NWG, THR, 0, stream>>>(w_ih_f, w_hh_f, b_ih_f, b_hh_f,
                                       w_ih_r, w_hh_r, b_ih_r, b_hh_r,
                                       xb, hb, flags, out);
}